// Round 1
// baseline (3911.708 us; speedup 1.0000x reference)
//
#include <hip/hip_runtime.h>

#define SS   2048
#define DKK  64
#define NH   16
#define RT   16     // q rows per block
#define TT   512    // threads per block (8 waves)
#define ESTR 2052   // padded e_row stride (floats): 16B-aligned, 2-way-free LDS banks

__global__ __launch_bounds__(TT) void attn_fwd(
    const float* __restrict__ Q,
    const float* __restrict__ K,
    const float* __restrict__ V,
    const int*   __restrict__ M,
    float* __restrict__ outp,
    float* __restrict__ attn)
{
    __shared__ float e_row[RT * ESTR];   // ~131 KB: unnormalized exp(scores) panel
    __shared__ float zred[RT * 64];      // 4 KB: per-(row, kgroup) partial sums
    __shared__ float zinv[RT];

    const int bh  = blockIdx.y;      // 0..63  (b*H + h)
    const int b   = bh >> 4;         // H == 16
    const int q0  = blockIdx.x * RT;
    const int tid = threadIdx.x;

    const float* Kb = K + (size_t)bh * SS * DKK;
    const float* Vb = V + (size_t)bh * SS * DKK;
    const float* Qb = Q + ((size_t)bh * SS + q0) * DKK;
    const int*   Mb = M + ((size_t)b * SS + q0) * SS;

    // ---------------- Phase 1: e = exp(masked score), Z partials ----------------
    // thread -> (row pair rp = tid&7, k group kg = tid>>3); k = kg + 64*j
    {
        const int rp = tid & 7;
        const int kg = tid >> 3;         // 0..63
        const int r0 = rp * 2;
        const int r1 = r0 + 1;

        // q rows in registers, pre-scaled by 1/sqrt(64)
        float qa[DKK], qb[DKK];
        {
            const float4* A  = (const float4*)(Qb + (size_t)r0 * DKK);
            const float4* Bq = (const float4*)(Qb + (size_t)r1 * DKK);
            #pragma unroll
            for (int c = 0; c < DKK/4; ++c) {
                float4 x = A[c], y = Bq[c];
                qa[4*c+0]=x.x*0.125f; qa[4*c+1]=x.y*0.125f; qa[4*c+2]=x.z*0.125f; qa[4*c+3]=x.w*0.125f;
                qb[4*c+0]=y.x*0.125f; qb[4*c+1]=y.y*0.125f; qb[4*c+2]=y.z*0.125f; qb[4*c+3]=y.w*0.125f;
            }
        }

        float z0 = 0.f, z1 = 0.f;
        #pragma unroll 1
        for (int j = 0; j < SS/64; ++j) {
            const int k = kg + 64*j;
            const float4* Kv = (const float4*)(Kb + (size_t)k * DKK);
            float s0 = 0.f, s1 = 0.f;
            #pragma unroll
            for (int c = 0; c < DKK/4; ++c) {
                float4 kv = Kv[c];
                s0 += qa[4*c+0]*kv.x + qa[4*c+1]*kv.y + qa[4*c+2]*kv.z + qa[4*c+3]*kv.w;
                s1 += qb[4*c+0]*kv.x + qb[4*c+1]*kv.y + qb[4*c+2]*kv.z + qb[4*c+3]*kv.w;
            }
            const int m0 = Mb[(size_t)r0 * SS + k];
            const int m1 = Mb[(size_t)r1 * SS + k];
            // scores are O(1); exp(s) without max-subtraction is fp32-safe here
            const float e0 = m0 ? __expf(s0) : 0.f;
            const float e1 = m1 ? __expf(s1) : 0.f;
            e_row[r0*ESTR + k] = e0;
            e_row[r1*ESTR + k] = e1;
            z0 += e0; z1 += e1;
        }
        zred[r0*64 + kg] = z0;
        zred[r1*64 + kg] = z1;
    }
    __syncthreads();

    if (tid < RT) {
        float z = 0.f;
        #pragma unroll
        for (int g = 0; g < 64; ++g) z += zred[tid*64 + g];
        zinv[tid] = 1.0f / z;
    }
    __syncthreads();

    // ---------------- attn = e * zinv  (coalesced float4 stores) ----------------
    for (int idx = tid; idx < RT*SS/4; idx += TT) {
        const int r  = idx >> 9;          // SS/4 = 512 float4 per row
        const int c4 = idx & 511;
        const float zi = zinv[r];
        const float4 e4 = *(const float4*)&e_row[r*ESTR + 4*c4];
        const float4 a4 = make_float4(e4.x*zi, e4.y*zi, e4.z*zi, e4.w*zi);
        *(float4*)&attn[((size_t)bh*SS + (size_t)(q0 + r))*SS + 4*c4] = a4;
    }

    // ---------------- Phase 2: out = (e @ V) * zinv ----------------
    // thread -> (d = tid&63 on lanes for coalesced V, wave kw partitions k)
    float acc[RT];
    const int d  = tid & 63;
    const int kw = tid >> 6;              // wave id 0..7
    #pragma unroll
    for (int r = 0; r < RT; ++r) acc[r] = 0.f;
    {
        const int kbase = kw * (SS/8);
        #pragma unroll 1
        for (int kb = 0; kb < SS/8; kb += 4) {
            const int k = kbase + kb;
            const float v0 = Vb[(size_t)(k+0)*DKK + d];
            const float v1 = Vb[(size_t)(k+1)*DKK + d];
            const float v2 = Vb[(size_t)(k+2)*DKK + d];
            const float v3 = Vb[(size_t)(k+3)*DKK + d];
            #pragma unroll
            for (int r = 0; r < RT; ++r) {
                const float4 e4 = *(const float4*)&e_row[r*ESTR + k];  // broadcast read
                acc[r] += e4.x*v0 + e4.y*v1 + e4.z*v2 + e4.w*v3;
            }
        }
    }
    __syncthreads();   // everyone done reading e_row before we reuse it
    {
        float* pred = e_row;              // reuse as [8][RT][64]
        #pragma unroll
        for (int r = 0; r < RT; ++r)
            pred[(kw*RT + r)*64 + d] = acc[r];
    }
    __syncthreads();
    {
        const float* pred = e_row;
        for (int idx = tid; idx < RT*DKK; idx += TT) {
            const int r  = idx >> 6;
            const int dd = idx & 63;
            float s = 0.f;
            #pragma unroll
            for (int g = 0; g < 8; ++g) s += pred[(g*RT + r)*64 + dd];
            outp[((size_t)bh*SS + (size_t)(q0 + r))*DKK + dd] = s * zinv[r];
        }
    }
}

extern "C" void kernel_launch(void* const* d_in, const int* in_sizes, int n_in,
                              void* d_out, int out_size, void* d_ws, size_t ws_size,
                              hipStream_t stream) {
    const float* Q = (const float*)d_in[0];
    const float* K = (const float*)d_in[1];
    const float* V = (const float*)d_in[2];
    const int*   M = (const int*)d_in[3];
    float* outp = (float*)d_out;
    float* attn = outp + (size_t)4 * NH * SS * DKK;   // out first, then attn
    dim3 grid(SS / RT, 4 * NH);
    attn_fwd<<<grid, TT, 0, stream>>>(Q, K, V, M, outp, attn);
}